// Round 1
// baseline (5523.726 us; speedup 1.0000x reference)
//
#include <hip/hip_runtime.h>
#include <math.h>

#define NNODES 10000
#define NEDGES 50000
#define ND 1152      // node feature dim = 128*(1+3+5)
#define MUL 128
#define NI 384
#define WNW 1408     // 11 paths * 128
#define EDIM 20

// ---- constants (derived analytically from the reference _real_w3j) ----
#define CK1 0.5773502691896258f     // 1/sqrt(3)
#define CK2 0.4472135954999579f     // 1/sqrt(5)
#define A2C 0.31622776601683794f    // 1/sqrt(10)
#define A0A (-0.18257418583505536f) // -1/sqrt(30)
#define A0B 0.3651483716701107f     // 2/sqrt(30)
#define B1C 0.11952286093343936f    // 1/sqrt(70)
#define B2C 0.23904572186687873f    // 2/sqrt(70)
#define B3C 0.20701966780270626f    // sqrt(3/70)
#define PW0 0.5773502691896258f     // sqrt(1/3)
#define PW1 0.8660254037844386f     // sqrt(3/4)
#define PW2 1.1180339887498949f     // sqrt(5/4)
#define INV128 0.08838834764831845f // 1/sqrt(128)

__device__ __forceinline__ float silu_f(float v) { return v / (1.f + expf(-v)); }

// ============================================================================
// Generic tiled GEMM: C[M x N] = epi(A[M x K] @ B[K x N] + bias)
// 64x64 tile, BK=32, 256 threads, 4x4 micro-tile per thread.
// AMODE 0: A plain (lda).  AMODE 1: A = s0 edge assembly (gather + dots).
// DUAL: C = (A@B + bias) * (A2@B2 + bias2)   (for tp_w)
// ============================================================================
template<int AMODE, bool SILU, bool DUAL>
__global__ __launch_bounds__(256) void gemm_mlp(
    const float* __restrict__ A, int lda,
    const float* __restrict__ B, int ldb, const float* __restrict__ bias,
    const float* __restrict__ A2, const float* __restrict__ B2,
    const float* __restrict__ bias2,
    float* __restrict__ C, int ldc, int M, int K,
    const float* __restrict__ xg, const int* __restrict__ ei,
    const float* __restrict__ dots)
{
    __shared__ float As[64][33];
    __shared__ float Bs[32][65];
    __shared__ float As2[DUAL ? 64 : 1][33];
    __shared__ float Bs2[DUAL ? 32 : 1][65];

    const int tid = threadIdx.x;
    const int tx = tid & 15, ty = tid >> 4;
    const int rowBase = blockIdx.y << 6;
    const int n0 = blockIdx.x << 6;

    float acc[16];
    float acc2[DUAL ? 16 : 1];
#pragma unroll
    for (int i = 0; i < 16; ++i) acc[i] = 0.f;
    if constexpr (DUAL) {
#pragma unroll
        for (int i = 0; i < 16; ++i) acc2[i] = 0.f;
    }

    for (int k0 = 0; k0 < K; k0 += 32) {
#pragma unroll
        for (int i = 0; i < 8; ++i) {
            int idx = tid + (i << 8);
            int ar = idx >> 5, ak = idx & 31;
            int row = rowBase + ar, k = k0 + ak;
            float v = 0.f, v2 = 0.f;
            if (row < M && k < K) {
                if constexpr (AMODE == 0) {
                    v = A[(size_t)row * lda + k];
                } else {
                    if (k < 128)      v = xg[(size_t)ei[row] * ND + k];
                    else if (k < 256) v = xg[(size_t)ei[NEDGES + row] * ND + (k - 128)];
                    else              v = dots[(size_t)row * 256 + (k - 256)];
                }
                if constexpr (DUAL) v2 = A2[(size_t)row * lda + k];
            }
            As[ar][ak] = v;
            if constexpr (DUAL) As2[ar][ak] = v2;
        }
#pragma unroll
        for (int i = 0; i < 8; ++i) {
            int idx = tid + (i << 8);
            int bk = idx >> 6, bn = idx & 63;
            int k = k0 + bk;
            float v = 0.f, v2 = 0.f;
            if (k < K) {
                v = B[(size_t)k * ldb + n0 + bn];
                if constexpr (DUAL) v2 = B2[(size_t)k * ldb + n0 + bn];
            }
            Bs[bk][bn] = v;
            if constexpr (DUAL) Bs2[bk][bn] = v2;
        }
        __syncthreads();
#pragma unroll
        for (int kk = 0; kk < 32; ++kk) {
            float a[4], b[4];
#pragma unroll
            for (int ii = 0; ii < 4; ++ii) a[ii] = As[(ty << 2) + ii][kk];
#pragma unroll
            for (int jj = 0; jj < 4; ++jj) b[jj] = Bs[kk][(tx << 2) + jj];
#pragma unroll
            for (int ii = 0; ii < 4; ++ii)
#pragma unroll
                for (int jj = 0; jj < 4; ++jj)
                    acc[ii * 4 + jj] = fmaf(a[ii], b[jj], acc[ii * 4 + jj]);
            if constexpr (DUAL) {
                float c[4], d[4];
#pragma unroll
                for (int ii = 0; ii < 4; ++ii) c[ii] = As2[(ty << 2) + ii][kk];
#pragma unroll
                for (int jj = 0; jj < 4; ++jj) d[jj] = Bs2[kk][(tx << 2) + jj];
#pragma unroll
                for (int ii = 0; ii < 4; ++ii)
#pragma unroll
                    for (int jj = 0; jj < 4; ++jj)
                        acc2[ii * 4 + jj] = fmaf(c[ii], d[jj], acc2[ii * 4 + jj]);
            }
        }
        __syncthreads();
    }
#pragma unroll
    for (int ii = 0; ii < 4; ++ii) {
        int row = rowBase + (ty << 2) + ii;
        if (row >= M) continue;
#pragma unroll
        for (int jj = 0; jj < 4; ++jj) {
            int col = n0 + (tx << 2) + jj;
            float v = acc[ii * 4 + jj] + bias[col];
            if constexpr (SILU) v = silu_f(v);
            if constexpr (DUAL) v = v * (acc2[ii * 4 + jj] + bias2[col]);
            C[(size_t)row * ldc + col] = v;
        }
    }
}

// ============================================================================
// o3_linear GEMM: out[n,v,m] = inv * sum_u in[n,u,m] * W_l[u,v]  (+ b0 if z==0)
// blockIdx.z = component (0: scalar, 1-3: l=1, 4-8: l=2). K=N=128.
// ============================================================================
template<bool BIAS>
__global__ __launch_bounds__(256) void gemm_o3(
    const float* __restrict__ Ain,
    const float* __restrict__ W0p, const float* __restrict__ W1p,
    const float* __restrict__ W2p, const float* __restrict__ b0p,
    float* __restrict__ C, int M)
{
    __shared__ float As[64][33];
    __shared__ float Bs[32][65];

    const int z = blockIdx.z;
    int off, stride;
    const float* W;
    if (z == 0)      { off = 0;             stride = 1; W = W0p; }
    else if (z < 4)  { off = 128 + (z - 1); stride = 3; W = W1p; }
    else             { off = 512 + (z - 4); stride = 5; W = W2p; }

    const int tid = threadIdx.x;
    const int tx = tid & 15, ty = tid >> 4;
    const int rowBase = blockIdx.y << 6;
    const int n0 = blockIdx.x << 6;

    float acc[16];
#pragma unroll
    for (int i = 0; i < 16; ++i) acc[i] = 0.f;

    for (int k0 = 0; k0 < 128; k0 += 32) {
#pragma unroll
        for (int i = 0; i < 8; ++i) {
            int idx = tid + (i << 8);
            int ar = idx >> 5, ak = idx & 31;
            int row = rowBase + ar;
            As[ar][ak] = (row < M)
                ? Ain[(size_t)row * ND + off + (size_t)(k0 + ak) * stride] : 0.f;
        }
#pragma unroll
        for (int i = 0; i < 8; ++i) {
            int idx = tid + (i << 8);
            int bk = idx >> 6, bn = idx & 63;
            Bs[bk][bn] = W[(size_t)(k0 + bk) * 128 + n0 + bn];
        }
        __syncthreads();
#pragma unroll
        for (int kk = 0; kk < 32; ++kk) {
            float a[4], b[4];
#pragma unroll
            for (int ii = 0; ii < 4; ++ii) a[ii] = As[(ty << 2) + ii][kk];
#pragma unroll
            for (int jj = 0; jj < 4; ++jj) b[jj] = Bs[kk][(tx << 2) + jj];
#pragma unroll
            for (int ii = 0; ii < 4; ++ii)
#pragma unroll
                for (int jj = 0; jj < 4; ++jj)
                    acc[ii * 4 + jj] = fmaf(a[ii], b[jj], acc[ii * 4 + jj]);
        }
        __syncthreads();
    }
#pragma unroll
    for (int ii = 0; ii < 4; ++ii) {
        int row = rowBase + (ty << 2) + ii;
        if (row >= M) continue;
#pragma unroll
        for (int jj = 0; jj < 4; ++jj) {
            int col = n0 + (tx << 2) + jj;
            float v = acc[ii * 4 + jj] * INV128;
            if (BIAS && z == 0) v += b0p[col];
            C[(size_t)row * ND + off + (size_t)col * stride] = v;
        }
    }
}

// ============================================================================
// equiv_dot l=1/l=2 parts for s0:  dots[e,u] = v1s.v1d/sqrt3 ; dots[e,128+u] = v2s.v2d/sqrt5
// ============================================================================
__global__ void dots_kernel(const float* __restrict__ x, const int* __restrict__ ei,
                            float* __restrict__ dots)
{
    int idx = blockIdx.x * 256 + threadIdx.x;
    int e = idx >> 8, t = idx & 255;
    if (e >= NEDGES) return;
    const float* ps = x + (size_t)ei[e] * ND;
    const float* pd = x + (size_t)ei[NEDGES + e] * ND;
    float v;
    if (t < 128) {
        int u = 128 + t * 3;
        v = (ps[u] * pd[u] + ps[u + 1] * pd[u + 1] + ps[u + 2] * pd[u + 2]) * CK1;
    } else {
        int u = 512 + (t - 128) * 5;
        v = (ps[u] * pd[u] + ps[u + 1] * pd[u + 1] + ps[u + 2] * pd[u + 2]
             + ps[u + 3] * pd[u + 3] + ps[u + 4] * pd[u + 4]) * CK2;
    }
    dots[idx] = v;
}

// ============================================================================
// norm_gate f0 = [s, ||v1||_c, ||v2||_c]  (M rows)
// ============================================================================
__global__ void f0_kernel(const float* __restrict__ in, float* __restrict__ f0, int M)
{
    int idx = blockIdx.x * 256 + threadIdx.x;
    int r = idx / 384, t = idx - r * 384;
    if (r >= M) return;
    const float* p = in + (size_t)r * ND;
    float v;
    if (t < 128) v = p[t];
    else if (t < 256) {
        int u = 128 + (t - 128) * 3;
        v = sqrtf(p[u] * p[u] + p[u + 1] * p[u + 1] + p[u + 2] * p[u + 2]);
    } else {
        int u = 512 + (t - 256) * 5;
        v = sqrtf(p[u] * p[u] + p[u + 1] * p[u + 1] + p[u + 2] * p[u + 2]
                  + p[u + 3] * p[u + 3] + p[u + 4] * p[u + 4]);
    }
    f0[(size_t)r * 384 + t] = v;
}

// gate in place (pre, node stage): s := g_s ; v *= gate
__global__ void gate_pre_kernel(float* __restrict__ xp, const float* __restrict__ g)
{
    int idx = blockIdx.x * 256 + threadIdx.x;
    if (idx >= NNODES * ND) return;
    int n = idx / ND, k = idx - n * ND;
    const float* gr = g + (size_t)n * 384;
    if (k < 128)      xp[idx] = gr[k];
    else if (k < 512) xp[idx] *= gr[128 + (k - 128) / 3];
    else              xp[idx] *= gr[256 + (k - 512) / 5];
}

// gate out of place (post, edge chunk): gfij = gate(fij)
__global__ void gate_post_kernel(const float* __restrict__ fij, const float* __restrict__ g,
                                 float* __restrict__ gfij, int Ec)
{
    int idx = blockIdx.x * 256 + threadIdx.x;
    if (idx >= Ec * ND) return;
    int r = idx / ND, k = idx - r * ND;
    const float* gr = g + (size_t)r * 384;
    float v;
    if (k < 128)      v = gr[k];
    else if (k < 512) v = fij[idx] * gr[128 + (k - 128) / 3];
    else              v = fij[idx] * gr[256 + (k - 512) / 5];
    gfij[idx] = v;
}

// ============================================================================
// Depthwise Wigner tensor product, 11 paths. 2 edges / 256-thread block.
// ============================================================================
__global__ __launch_bounds__(256) void tp_kernel(
    const float* __restrict__ xp, const int* __restrict__ ei,
    const float* __restrict__ tpw, float* __restrict__ out, int e0, int Ec)
{
    int le = blockIdx.x * 2 + (threadIdx.x >> 7);
    int u = threadIdx.x & 127;
    if (le >= Ec) return;
    int e = e0 + le;
    const float* ps = xp + (size_t)ei[e] * ND;
    const float* pd = xp + (size_t)ei[NEDGES + e] * ND;

    float ss = ps[u], sd = pd[u];
    float a0 = ps[128 + u * 3], a1 = ps[129 + u * 3], a2 = ps[130 + u * 3];
    float b0 = pd[128 + u * 3], b1 = pd[129 + u * 3], b2 = pd[130 + u * 3];
    float c0 = ps[512 + u * 5], c1 = ps[513 + u * 5], c2 = ps[514 + u * 5],
          c3 = ps[515 + u * 5], c4 = ps[516 + u * 5];
    float d0 = pd[512 + u * 5], d1 = pd[513 + u * 5], d2 = pd[514 + u * 5],
          d3 = pd[515 + u * 5], d4 = pd[516 + u * 5];

    const float* w = tpw + (size_t)le * WNW + u;
    float w0 = w[0],      w1 = w[128],  w2 = w[256],  w3 = w[384],  w4 = w[512];
    float w5 = w[640],    w6 = w[768],  w7 = w[896],  w8 = w[1024], w9 = w[1152];
    float w10 = w[1280];

    float dab = a0 * b0 + a1 * b1 + a2 * b2;
    float dcd = c0 * d0 + c1 * d1 + c2 * d2 + c3 * d3 + c4 * d4;

    // l3 = 0
    float o_s = PW0 * (w0 * ss * sd + w4 * CK1 * dab + w9 * CK2 * dcd);

    // l3 = 1:  (1,2,1) contraction R (v1_s x v2_d),  (2,1,1) contraction U (v2_s x v1_d)
    float R0 = A0A * a0 * d2 + A2C * (a1 * d1 + a2 * d0 - a0 * d4);
    float R1 = A0B * a1 * d2 + A2C * (a0 * d1 + a2 * d3);
    float R2 = A0A * a2 * d2 + A2C * (a1 * d3 + a0 * d0 + a2 * d4);
    float U0 = A0A * b0 * c2 + A2C * (b1 * c1 + b2 * c0 - b0 * c4);
    float U1 = A0B * b1 * c2 + A2C * (b0 * c1 + b2 * c3);
    float U2 = A0A * b2 * c2 + A2C * (b1 * c3 + b0 * c0 + b2 * c4);
    float o1_0 = PW1 * (CK1 * (w1 * ss * b0 + w3 * a0 * sd) + w6 * R0 + w8 * U0);
    float o1_1 = PW1 * (CK1 * (w1 * ss * b1 + w3 * a1 * sd) + w6 * R1 + w8 * U1);
    float o1_2 = PW1 * (CK1 * (w1 * ss * b2 + w3 * a2 * sd) + w6 * R2 + w8 * U2);

    // l3 = 2:  (1,1,2) contraction S,  (2,2,2) contraction V
    float S0 = A2C * (a0 * b2 + a2 * b0);
    float S1 = A2C * (a0 * b1 + a1 * b0);
    float S2 = A0A * (a0 * b0 + a2 * b2) + A0B * a1 * b1;
    float S3 = A2C * (a1 * b2 + a2 * b1);
    float S4 = A2C * (a2 * b2 - a0 * b0);
    float V0 = -B2C * (c0 * d2 + c2 * d0) + B3C * (c1 * d3 + c3 * d1);
    float V1 =  B3C * (c0 * d3 + c3 * d0) - B3C * (c1 * d4 + c4 * d1)
              + B1C * (c1 * d2 + c2 * d1);
    float V2 = -B2C * (c0 * d0 + c4 * d4) + B1C * (c1 * d1 + c3 * d3) + B2C * c2 * d2;
    float V3 =  B3C * (c0 * d1 + c1 * d0) + B3C * (c3 * d4 + c4 * d3)
              + B1C * (c2 * d3 + c3 * d2);
    float V4 = -B2C * (c2 * d4 + c4 * d2) - B3C * c1 * d1 + B3C * c3 * d3;
    float o2_0 = PW2 * (CK2 * (w2 * ss * d0 + w7 * c0 * sd) + w5 * S0 + w10 * V0);
    float o2_1 = PW2 * (CK2 * (w2 * ss * d1 + w7 * c1 * sd) + w5 * S1 + w10 * V1);
    float o2_2 = PW2 * (CK2 * (w2 * ss * d2 + w7 * c2 * sd) + w5 * S2 + w10 * V2);
    float o2_3 = PW2 * (CK2 * (w2 * ss * d3 + w7 * c3 * sd) + w5 * S3 + w10 * V3);
    float o2_4 = PW2 * (CK2 * (w2 * ss * d4 + w7 * c4 * sd) + w5 * S4 + w10 * V4);

    float* po = out + (size_t)e * ND;
    po[u] = o_s;
    po[128 + u * 3] = o1_0; po[129 + u * 3] = o1_1; po[130 + u * 3] = o1_2;
    po[512 + u * 5] = o2_0; po[513 + u * 5] = o2_1; po[514 + u * 5] = o2_2;
    po[515 + u * 5] = o2_3; po[516 + u * 5] = o2_4;
}

// ============================================================================
extern "C" void kernel_launch(void* const* d_in, const int* in_sizes, int n_in,
                              void* d_out, int out_size, void* d_ws, size_t ws_size,
                              hipStream_t stream)
{
    const float* x         = (const float*)d_in[0];
    const float* edge_attr = (const float*)d_in[1];
    const int*   ei        = (const int*)  d_in[2];
    const float* W_pre0    = (const float*)d_in[3];
    const float* W_pre1    = (const float*)d_in[4];
    const float* W_pre2    = (const float*)d_in[5];
    const float* b_pre0    = (const float*)d_in[6];
    const float* ngpre_W1  = (const float*)d_in[7];
    const float* ngpre_b1  = (const float*)d_in[8];
    const float* ngpre_W2  = (const float*)d_in[9];
    const float* ngpre_b2  = (const float*)d_in[10];
    const float* es_W1     = (const float*)d_in[11];
    const float* es_b1     = (const float*)d_in[12];
    const float* es_W2     = (const float*)d_in[13];
    const float* es_b2     = (const float*)d_in[14];
    const float* er_W1     = (const float*)d_in[15];
    const float* er_b1     = (const float*)d_in[16];
    const float* er_W2     = (const float*)d_in[17];
    const float* er_b2     = (const float*)d_in[18];
    const float* ngpost_W1 = (const float*)d_in[19];
    const float* ngpost_b1 = (const float*)d_in[20];
    const float* ngpost_W2 = (const float*)d_in[21];
    const float* ngpost_b2 = (const float*)d_in[22];
    const float* W_post0   = (const float*)d_in[23];
    const float* W_post1   = (const float*)d_in[24];
    const float* W_post2   = (const float*)d_in[25];
    float* out = (float*)d_out;
    float* ws  = (float*)d_ws;

    // workspace layout (floats)
    const size_t off_xp  = 0;                        // N*1152 = 11.52M
    const size_t off_hes = off_xp + (size_t)NNODES * ND;
    const size_t off_her = off_hes + (size_t)NEDGES * 128;
    const size_t off_big = off_her + (size_t)NEDGES * 128;   // 24.32M
    float* xp   = ws + off_xp;
    float* hes  = ws + off_hes;
    float* her  = ws + off_her;
    float* bigp = ws + off_big;

    long ws_floats = (long)(ws_size / 4);
    long big = ws_floats - (long)off_big;
    long ecmax = big / 2304;           // post stage needs 2304 floats/edge
    if (ecmax > NEDGES) ecmax = NEDGES;
    if (ecmax < 1) ecmax = 1;
    int NC = (int)((NEDGES + ecmax - 1) / ecmax);
    int Ec = (NEDGES + NC - 1) / NC;

    // ---- edge feature MLPs (full E) ----
    dots_kernel<<<NEDGES, 256, 0, stream>>>(x, ei, bigp);

    dim3 gE(2, (NEDGES + 63) / 64);
    gemm_mlp<1, true, false><<<gE, 256, 0, stream>>>(
        nullptr, 0, es_W1, 128, es_b1, nullptr, nullptr, nullptr,
        hes, 128, NEDGES, 512, x, ei, bigp);
    gemm_mlp<0, true, false><<<gE, 256, 0, stream>>>(
        edge_attr, EDIM, er_W1, 128, er_b1, nullptr, nullptr, nullptr,
        her, 128, NEDGES, EDIM, nullptr, nullptr, nullptr);

    // ---- node pre block: x' = norm_gate(o3_linear(x)) ----
    dim3 gO3p(2, (NNODES + 63) / 64, 9);
    gemm_o3<true><<<gO3p, 256, 0, stream>>>(x, W_pre0, W_pre1, W_pre2, b_pre0, xp, NNODES);

    float* f0n = bigp;
    float* hb  = bigp + (size_t)NNODES * 384;
    float* gb  = hb + (size_t)NNODES * 384;
    f0_kernel<<<((size_t)NNODES * 384 + 255) / 256, 256, 0, stream>>>(xp, f0n, NNODES);
    dim3 gNGp(6, (NNODES + 63) / 64);
    gemm_mlp<0, true, false><<<gNGp, 256, 0, stream>>>(
        f0n, 384, ngpre_W1, 384, ngpre_b1, nullptr, nullptr, nullptr,
        hb, 384, NNODES, 384, nullptr, nullptr, nullptr);
    gemm_mlp<0, false, false><<<gNGp, 256, 0, stream>>>(
        hb, 384, ngpre_W2, 384, ngpre_b2, nullptr, nullptr, nullptr,
        gb, 384, NNODES, 384, nullptr, nullptr, nullptr);
    gate_pre_kernel<<<((size_t)NNODES * ND + 255) / 256, 256, 0, stream>>>(xp, gb);

    // ---- edge chunks: tp_w -> TP -> norm_gate -> o3_linear ----
    for (int c = 0; c < NC; ++c) {
        int e0 = c * Ec;
        int ec = NEDGES - e0; if (ec > Ec) ec = Ec;
        if (ec <= 0) break;

        float* tpw = bigp;
        dim3 gT(22, (ec + 63) / 64);
        gemm_mlp<0, false, true><<<gT, 256, 0, stream>>>(
            hes + (size_t)e0 * 128, 128, es_W2, WNW, es_b2,
            her + (size_t)e0 * 128, er_W2, er_b2,
            tpw, WNW, ec, 128, nullptr, nullptr, nullptr);

        tp_kernel<<<(ec + 1) / 2, 256, 0, stream>>>(xp, ei, tpw, out, e0, ec);

        float* f0p  = bigp;
        float* h1p  = f0p + (size_t)ec * 384;
        float* gp   = h1p + (size_t)ec * 384;
        float* gfij = gp  + (size_t)ec * 384;

        f0_kernel<<<((size_t)ec * 384 + 255) / 256, 256, 0, stream>>>(
            out + (size_t)e0 * ND, f0p, ec);
        dim3 gNG(6, (ec + 63) / 64);
        gemm_mlp<0, true, false><<<gNG, 256, 0, stream>>>(
            f0p, 384, ngpost_W1, 384, ngpost_b1, nullptr, nullptr, nullptr,
            h1p, 384, ec, 384, nullptr, nullptr, nullptr);
        gemm_mlp<0, false, false><<<gNG, 256, 0, stream>>>(
            h1p, 384, ngpost_W2, 384, ngpost_b2, nullptr, nullptr, nullptr,
            gp, 384, ec, 384, nullptr, nullptr, nullptr);
        gate_post_kernel<<<((size_t)ec * ND + 255) / 256, 256, 0, stream>>>(
            out + (size_t)e0 * ND, gp, gfij, ec);

        dim3 gO3q(2, (ec + 63) / 64, 9);
        gemm_o3<false><<<gO3q, 256, 0, stream>>>(
            gfij, W_post0, W_post1, W_post2, nullptr, out + (size_t)e0 * ND, ec);
    }
}

// Round 2
// 2731.548 us; speedup vs baseline: 2.0222x; 2.0222x over previous
//
#include <hip/hip_runtime.h>
#include <math.h>

#define NNODES 10000
#define NEDGES 50000
#define ND 1152
#define MUL 128
#define WNW 1408
#define EDIM 20

#define CK1 0.5773502691896258f
#define CK2 0.4472135954999579f
#define A2C 0.31622776601683794f
#define A0A (-0.18257418583505536f)
#define A0B 0.3651483716701107f
#define B1C 0.11952286093343936f
#define B2C 0.23904572186687873f
#define B3C 0.20701966780270626f
#define PW0 0.5773502691896258f
#define PW1 0.8660254037844386f
#define PW2 1.1180339887498949f
#define INV128 0.08838834764831845f

__device__ __forceinline__ float silu_f(float v) { return v / (1.f + expf(-v)); }

// ============================================================================
// 128x128-tile fp32 GEMM, 256 threads, 8x8 micro-tile (2x2 blocks of 4x4),
// A transposed in LDS so all fragment reads are ds_read_b128.
// AMODE 0: plain A[lda]. 1: s0 edge assembly (gather x + dots), K=512.
//       2: strided o3 component read from interleaved x (off/stride by z).
//       3: plane A (A += z*M*lda).
// OMODE 0: plain C[ldc]. 1: strided o3 component write to interleaved out.
//       2: plane C (C += z*M*ldc).
// O3S: scale INV128 (+ bias at z==0 only). SILU / FMUL epilogue fusions.
// ============================================================================
template<int AMODE, int OMODE, bool SILU, bool FMUL, bool O3S>
__global__ __launch_bounds__(256) void gemm128(
    const float* __restrict__ A, int lda,
    const float* __restrict__ B, int ldb,
    const float* __restrict__ W1p, const float* __restrict__ W2p,
    const float* __restrict__ bias, const float* __restrict__ M2,
    float* __restrict__ C, int ldc, int M, int K,
    const float* __restrict__ xg, const int* __restrict__ ei,
    const float* __restrict__ dots)
{
    __shared__ float Ast[32][132];
    __shared__ float Bs[32][132];

    const int tid = threadIdx.x;
    const int tx = tid & 15, ty = tid >> 4;
    const int rowBase = blockIdx.y << 7;
    const int n0 = blockIdx.x << 7;
    const int z = blockIdx.z;

    int off = 0, stride = 1;
    if constexpr (AMODE == 2 || AMODE == 3 || OMODE == 1 || O3S) {
        if (z == 0)      { off = 0;             stride = 1; }
        else if (z < 4)  { off = 128 + (z - 1); stride = 3; }
        else             { off = 512 + (z - 4); stride = 5; }
    }
    const float* Bz = B;
    if constexpr (AMODE >= 2) {   // o3 weight select by l
        if (z >= 1 && z < 4) Bz = W1p;
        else if (z >= 4)     Bz = W2p;
    }
    const float* Ab = A;
    if constexpr (AMODE == 3) Ab = A + (size_t)z * M * lda;
    float* Cb = C;
    if constexpr (OMODE == 2) Cb = C + (size_t)z * M * ldc;

    float acc[2][2][4][4] = {};

    for (int k0 = 0; k0 < K; k0 += 32) {
        // ---- stage A (transposed into LDS) ----
#pragma unroll
        for (int i = 0; i < 4; ++i) {
            int f4 = tid + (i << 8);          // 0..1023
            int row = f4 >> 3;                // 0..127
            int kq  = (f4 & 7) << 2;          // 0,4,..,28
            int grow = rowBase + row, gk = k0 + kq;
            float4 v = make_float4(0.f, 0.f, 0.f, 0.f);
            if (grow < M) {
                if constexpr (AMODE == 0 || AMODE == 3) {
                    if (gk + 4 <= K) {
                        v = *(const float4*)&Ab[(size_t)grow * lda + gk];
                    } else {
                        float t[4] = {0.f, 0.f, 0.f, 0.f};
#pragma unroll
                        for (int j = 0; j < 4; ++j)
                            if (gk + j < K) t[j] = Ab[(size_t)grow * lda + gk + j];
                        v = make_float4(t[0], t[1], t[2], t[3]);
                    }
                } else if constexpr (AMODE == 1) {
                    if (gk < 128)
                        v = *(const float4*)&xg[(size_t)ei[grow] * ND + gk];
                    else if (gk < 256)
                        v = *(const float4*)&xg[(size_t)ei[NEDGES + grow] * ND + (gk - 128)];
                    else
                        v = *(const float4*)&dots[(size_t)grow * 256 + (gk - 256)];
                } else {  // AMODE 2: strided component from interleaved rows
                    const float* p = &Ab[(size_t)grow * ND + off];
                    v.x = p[(gk + 0) * stride];
                    v.y = p[(gk + 1) * stride];
                    v.z = p[(gk + 2) * stride];
                    v.w = p[(gk + 3) * stride];
                }
            }
            Ast[kq + 0][row] = v.x;
            Ast[kq + 1][row] = v.y;
            Ast[kq + 2][row] = v.z;
            Ast[kq + 3][row] = v.w;
        }
        // ---- stage B ----
#pragma unroll
        for (int i = 0; i < 4; ++i) {
            int f4 = tid + (i << 8);
            int bk = f4 >> 5;                 // 0..31
            int nq = (f4 & 31) << 2;          // 0..124
            float4 v = make_float4(0.f, 0.f, 0.f, 0.f);
            if (k0 + bk < K)
                v = *(const float4*)&Bz[(size_t)(k0 + bk) * ldb + n0 + nq];
            *(float4*)&Bs[bk][nq] = v;
        }
        __syncthreads();
#pragma unroll
        for (int kk = 0; kk < 32; ++kk) {
            float4 a0 = *(const float4*)&Ast[kk][(ty << 2)];
            float4 a1 = *(const float4*)&Ast[kk][64 + (ty << 2)];
            float4 b0 = *(const float4*)&Bs[kk][(tx << 2)];
            float4 b1 = *(const float4*)&Bs[kk][64 + (tx << 2)];
            float ar[2][4] = {{a0.x, a0.y, a0.z, a0.w}, {a1.x, a1.y, a1.z, a1.w}};
            float br[2][4] = {{b0.x, b0.y, b0.z, b0.w}, {b1.x, b1.y, b1.z, b1.w}};
#pragma unroll
            for (int h = 0; h < 2; ++h)
#pragma unroll
                for (int g = 0; g < 2; ++g)
#pragma unroll
                    for (int ii = 0; ii < 4; ++ii)
#pragma unroll
                        for (int jj = 0; jj < 4; ++jj)
                            acc[h][g][ii][jj] = fmaf(ar[h][ii], br[g][jj], acc[h][g][ii][jj]);
        }
        __syncthreads();
    }

    // ---- epilogue ----
#pragma unroll
    for (int h = 0; h < 2; ++h) {
#pragma unroll
        for (int ii = 0; ii < 4; ++ii) {
            int row = rowBase + (h << 6) + (ty << 2) + ii;
            if (row >= M) continue;
#pragma unroll
            for (int g = 0; g < 2; ++g) {
                int colq = n0 + (g << 6) + (tx << 2);
                float o[4];
#pragma unroll
                for (int jj = 0; jj < 4; ++jj) {
                    float v = acc[h][g][ii][jj];
                    int col = colq + jj;
                    if constexpr (O3S) {
                        v *= INV128;
                        if (bias && z == 0) v += bias[col];
                    } else {
                        if (bias) v += bias[col];
                    }
                    if constexpr (SILU) v = silu_f(v);
                    if constexpr (FMUL) v *= M2[(size_t)row * ldc + col];
                    o[jj] = v;
                }
                if constexpr (OMODE == 1) {
                    float* p = &Cb[(size_t)row * ND + off];
#pragma unroll
                    for (int jj = 0; jj < 4; ++jj) p[(colq + jj) * stride] = o[jj];
                } else {
                    *(float4*)&Cb[(size_t)row * ldc + colq] =
                        make_float4(o[0], o[1], o[2], o[3]);
                }
            }
        }
    }
}

// ============================================================================
// dots for s0 (reads interleaved input x)
// ============================================================================
__global__ void dots_kernel(const float* __restrict__ x, const int* __restrict__ ei,
                            float* __restrict__ dots)
{
    int idx = blockIdx.x * 256 + threadIdx.x;
    int e = idx >> 8, t = idx & 255;
    if (e >= NEDGES) return;
    const float* ps = x + (size_t)ei[e] * ND;
    const float* pd = x + (size_t)ei[NEDGES + e] * ND;
    float v;
    if (t < 128) {
        int u = 128 + t * 3;
        v = (ps[u] * pd[u] + ps[u + 1] * pd[u + 1] + ps[u + 2] * pd[u + 2]) * CK1;
    } else {
        int u = 512 + (t - 128) * 5;
        v = (ps[u] * pd[u] + ps[u + 1] * pd[u + 1] + ps[u + 2] * pd[u + 2]
             + ps[u + 3] * pd[u + 3] + ps[u + 4] * pd[u + 4]) * CK2;
    }
    dots[idx] = v;
}

// ============================================================================
// f0 = [s, ||v1||_c, ||v2||_c] from PLANE layout (plane stride M*128)
// ============================================================================
__global__ void f0_kernel(const float* __restrict__ in, float* __restrict__ f0, int M)
{
    int idx = blockIdx.x * 256 + threadIdx.x;
    int r = idx / 384, t = idx - r * 384;
    if (r >= M) return;
    size_t P = (size_t)M * 128;
    const float* p = in + (size_t)r * 128;
    float v;
    if (t < 128) v = p[t];
    else if (t < 256) {
        int u = t - 128;
        float x1 = p[P + u], x2 = p[2 * P + u], x3 = p[3 * P + u];
        v = sqrtf(x1 * x1 + x2 * x2 + x3 * x3);
    } else {
        int u = t - 256;
        float x1 = p[4 * P + u], x2 = p[5 * P + u], x3 = p[6 * P + u],
              x4 = p[7 * P + u], x5 = p[8 * P + u];
        v = sqrtf(x1 * x1 + x2 * x2 + x3 * x3 + x4 * x4 + x5 * x5);
    }
    f0[(size_t)r * 384 + t] = v;
}

// gate in place on PLANE layout. grid: (ceil(M*128/256), 9)
__global__ void gate_kernel(float* __restrict__ xp, const float* __restrict__ g, int M)
{
    int t = blockIdx.x * 256 + threadIdx.x;
    if (t >= M * 128) return;
    int z = blockIdx.y;
    int r = t >> 7, u = t & 127;
    float* p = xp + (size_t)z * M * 128 + t;
    const float* gr = g + (size_t)r * 384;
    if (z == 0)      *p = gr[u];
    else if (z < 4)  *p *= gr[128 + u];
    else             *p *= gr[256 + u];
}

// ============================================================================
// Wigner TP, plane layout in (xp) and out (fij). 2 edges per block.
// ============================================================================
__global__ __launch_bounds__(256) void tp_kernel(
    const float* __restrict__ xp, const int* __restrict__ ei,
    const float* __restrict__ tpw, float* __restrict__ fij, int e0, int ec)
{
    int le = blockIdx.x * 2 + (threadIdx.x >> 7);
    int u = threadIdx.x & 127;
    if (le >= ec) return;
    int e = e0 + le;
    const size_t NP = (size_t)NNODES * 128;
    const float* ps = xp + (size_t)ei[e] * 128 + u;
    const float* pd = xp + (size_t)ei[NEDGES + e] * 128 + u;

    float ss = ps[0], sd = pd[0];
    float a0 = ps[NP],     a1 = ps[2 * NP], a2 = ps[3 * NP];
    float b0 = pd[NP],     b1 = pd[2 * NP], b2 = pd[3 * NP];
    float c0 = ps[4 * NP], c1 = ps[5 * NP], c2 = ps[6 * NP],
          c3 = ps[7 * NP], c4 = ps[8 * NP];
    float d0 = pd[4 * NP], d1 = pd[5 * NP], d2 = pd[6 * NP],
          d3 = pd[7 * NP], d4 = pd[8 * NP];

    const float* w = tpw + (size_t)le * WNW + u;
    float w0 = w[0],    w1 = w[128],  w2 = w[256],  w3 = w[384],  w4 = w[512];
    float w5 = w[640],  w6 = w[768],  w7 = w[896],  w8 = w[1024], w9 = w[1152];
    float w10 = w[1280];

    float dab = a0 * b0 + a1 * b1 + a2 * b2;
    float dcd = c0 * d0 + c1 * d1 + c2 * d2 + c3 * d3 + c4 * d4;

    float o_s = PW0 * (w0 * ss * sd + w4 * CK1 * dab + w9 * CK2 * dcd);

    float R0 = A0A * a0 * d2 + A2C * (a1 * d1 + a2 * d0 - a0 * d4);
    float R1 = A0B * a1 * d2 + A2C * (a0 * d1 + a2 * d3);
    float R2 = A0A * a2 * d2 + A2C * (a1 * d3 + a0 * d0 + a2 * d4);
    float U0 = A0A * b0 * c2 + A2C * (b1 * c1 + b2 * c0 - b0 * c4);
    float U1 = A0B * b1 * c2 + A2C * (b0 * c1 + b2 * c3);
    float U2 = A0A * b2 * c2 + A2C * (b1 * c3 + b0 * c0 + b2 * c4);
    float o1_0 = PW1 * (CK1 * (w1 * ss * b0 + w3 * a0 * sd) + w6 * R0 + w8 * U0);
    float o1_1 = PW1 * (CK1 * (w1 * ss * b1 + w3 * a1 * sd) + w6 * R1 + w8 * U1);
    float o1_2 = PW1 * (CK1 * (w1 * ss * b2 + w3 * a2 * sd) + w6 * R2 + w8 * U2);

    float S0 = A2C * (a0 * b2 + a2 * b0);
    float S1 = A2C * (a0 * b1 + a1 * b0);
    float S2 = A0A * (a0 * b0 + a2 * b2) + A0B * a1 * b1;
    float S3 = A2C * (a1 * b2 + a2 * b1);
    float S4 = A2C * (a2 * b2 - a0 * b0);
    float V0 = -B2C * (c0 * d2 + c2 * d0) + B3C * (c1 * d3 + c3 * d1);
    float V1 =  B3C * (c0 * d3 + c3 * d0) - B3C * (c1 * d4 + c4 * d1)
              + B1C * (c1 * d2 + c2 * d1);
    float V2 = -B2C * (c0 * d0 + c4 * d4) + B1C * (c1 * d1 + c3 * d3) + B2C * c2 * d2;
    float V3 =  B3C * (c0 * d1 + c1 * d0) + B3C * (c3 * d4 + c4 * d3)
              + B1C * (c2 * d3 + c3 * d2);
    float V4 = -B2C * (c2 * d4 + c4 * d2) - B3C * c1 * d1 + B3C * c3 * d3;
    float o2_0 = PW2 * (CK2 * (w2 * ss * d0 + w7 * c0 * sd) + w5 * S0 + w10 * V0);
    float o2_1 = PW2 * (CK2 * (w2 * ss * d1 + w7 * c1 * sd) + w5 * S1 + w10 * V1);
    float o2_2 = PW2 * (CK2 * (w2 * ss * d2 + w7 * c2 * sd) + w5 * S2 + w10 * V2);
    float o2_3 = PW2 * (CK2 * (w2 * ss * d3 + w7 * c3 * sd) + w5 * S3 + w10 * V3);
    float o2_4 = PW2 * (CK2 * (w2 * ss * d4 + w7 * c4 * sd) + w5 * S4 + w10 * V4);

    size_t FP = (size_t)ec * 128;
    float* po = fij + (size_t)le * 128 + u;
    po[0] = o_s;
    po[FP] = o1_0;     po[2 * FP] = o1_1; po[3 * FP] = o1_2;
    po[4 * FP] = o2_0; po[5 * FP] = o2_1; po[6 * FP] = o2_2;
    po[7 * FP] = o2_3; po[8 * FP] = o2_4;
}

// ============================================================================
extern "C" void kernel_launch(void* const* d_in, const int* in_sizes, int n_in,
                              void* d_out, int out_size, void* d_ws, size_t ws_size,
                              hipStream_t stream)
{
    const float* x         = (const float*)d_in[0];
    const float* edge_attr = (const float*)d_in[1];
    const int*   ei        = (const int*)  d_in[2];
    const float* W_pre0    = (const float*)d_in[3];
    const float* W_pre1    = (const float*)d_in[4];
    const float* W_pre2    = (const float*)d_in[5];
    const float* b_pre0    = (const float*)d_in[6];
    const float* ngpre_W1  = (const float*)d_in[7];
    const float* ngpre_b1  = (const float*)d_in[8];
    const float* ngpre_W2  = (const float*)d_in[9];
    const float* ngpre_b2  = (const float*)d_in[10];
    const float* es_W1     = (const float*)d_in[11];
    const float* es_b1     = (const float*)d_in[12];
    const float* es_W2     = (const float*)d_in[13];
    const float* es_b2     = (const float*)d_in[14];
    const float* er_W1     = (const float*)d_in[15];
    const float* er_b1     = (const float*)d_in[16];
    const float* er_W2     = (const float*)d_in[17];
    const float* er_b2     = (const float*)d_in[18];
    const float* ngpost_W1 = (const float*)d_in[19];
    const float* ngpost_b1 = (const float*)d_in[20];
    const float* ngpost_W2 = (const float*)d_in[21];
    const float* ngpost_b2 = (const float*)d_in[22];
    const float* W_post0   = (const float*)d_in[23];
    const float* W_post1   = (const float*)d_in[24];
    const float* W_post2   = (const float*)d_in[25];
    float* out = (float*)d_out;
    float* ws  = (float*)d_ws;

    // fixed workspace: xp planes (9*N*128), hes, her
    float* xp    = ws;
    float* hes   = ws + (size_t)9 * NNODES * 128;               // 11.52M
    float* her   = hes + (size_t)NEDGES * 128;                  // +6.4M
    float* arena = her + (size_t)NEDGES * 128;                  // 24.32M fixed

    long ws_floats = (long)(ws_size / 4);
    long arena_f = ws_floats - (long)(24320000);
    long ec0 = arena_f / 3968;                                  // es2+tpw+fij slots
    if (ec0 > NEDGES) ec0 = NEDGES;
    if (ec0 < 1) ec0 = 1;
    int NC = (int)((NEDGES + ec0 - 1) / ec0);
    int Ec = (NEDGES + NC - 1) / NC;

    float* dots = arena;                                        // pre-loop use

    // ---- edge hidden MLPs (full E) ----
    dots_kernel<<<NEDGES, 256, 0, stream>>>(x, ei, dots);

    dim3 gE(1, (NEDGES + 127) / 128);
    gemm128<1, 0, true, false, false><<<gE, 256, 0, stream>>>(
        nullptr, 0, es_W1, 128, nullptr, nullptr, es_b1, nullptr,
        hes, 128, NEDGES, 512, x, ei, dots);
    gemm128<0, 0, true, false, false><<<gE, 256, 0, stream>>>(
        edge_attr, EDIM, er_W1, 128, nullptr, nullptr, er_b1, nullptr,
        her, 128, NEDGES, EDIM, nullptr, nullptr, nullptr);

    // ---- node pre: xp = norm_gate(o3_linear(x))  [plane layout] ----
    dim3 gO3p(1, (NNODES + 127) / 128, 9);
    gemm128<2, 2, false, false, true><<<gO3p, 256, 0, stream>>>(
        x, 0, W_pre0, 128, W_pre1, W_pre2, b_pre0, nullptr,
        xp, 128, NNODES, 128, nullptr, nullptr, nullptr);

    float* f0n = arena;
    float* hb  = f0n + (size_t)NNODES * 384;
    float* gb  = hb + (size_t)NNODES * 384;
    f0_kernel<<<((size_t)NNODES * 384 + 255) / 256, 256, 0, stream>>>(xp, f0n, NNODES);
    dim3 gNGp(3, (NNODES + 127) / 128);
    gemm128<0, 0, true, false, false><<<gNGp, 256, 0, stream>>>(
        f0n, 384, ngpre_W1, 384, nullptr, nullptr, ngpre_b1, nullptr,
        hb, 384, NNODES, 384, nullptr, nullptr, nullptr);
    gemm128<0, 0, false, false, false><<<gNGp, 256, 0, stream>>>(
        hb, 384, ngpre_W2, 384, nullptr, nullptr, ngpre_b2, nullptr,
        gb, 384, NNODES, 384, nullptr, nullptr, nullptr);
    dim3 gGp((NNODES * 128 + 255) / 256, 9);
    gate_kernel<<<gGp, 256, 0, stream>>>(xp, gb, NNODES);

    // ---- edge chunks ----
    for (int c = 0; c < NC; ++c) {
        int e0 = c * Ec;
        int ec = NEDGES - e0; if (ec > Ec) ec = Ec;
        if (ec <= 0) break;

        float* es2c = arena;
        float* tpwc = es2c + (size_t)Ec * 1408;
        float* fijc = tpwc + (size_t)Ec * 1408;
        dim3 gW(11, (ec + 127) / 128);
        gemm128<0, 0, false, false, false><<<gW, 256, 0, stream>>>(
            hes + (size_t)e0 * 128, 128, es_W2, WNW, nullptr, nullptr, es_b2, nullptr,
            es2c, WNW, ec, 128, nullptr, nullptr, nullptr);
        gemm128<0, 0, false, true, false><<<gW, 256, 0, stream>>>(
            her + (size_t)e0 * 128, 128, er_W2, WNW, nullptr, nullptr, er_b2, es2c,
            tpwc, WNW, ec, 128, nullptr, nullptr, nullptr);

        tp_kernel<<<(ec + 1) / 2, 256, 0, stream>>>(xp, ei, tpwc, fijc, e0, ec);

        // tpw dead: reuse its slot for f0/h1/g (3*384 = 1152 <= 1408)
        float* f0p = tpwc;
        float* h1p = f0p + (size_t)Ec * 384;
        float* gp  = h1p + (size_t)Ec * 384;
        f0_kernel<<<((size_t)ec * 384 + 255) / 256, 256, 0, stream>>>(fijc, f0p, ec);
        dim3 gNG(3, (ec + 127) / 128);
        gemm128<0, 0, true, false, false><<<gNG, 256, 0, stream>>>(
            f0p, 384, ngpost_W1, 384, nullptr, nullptr, ngpost_b1, nullptr,
            h1p, 384, ec, 384, nullptr, nullptr, nullptr);
        gemm128<0, 0, false, false, false><<<gNG, 256, 0, stream>>>(
            h1p, 384, ngpost_W2, 384, nullptr, nullptr, ngpost_b2, nullptr,
            gp, 384, ec, 384, nullptr, nullptr, nullptr);
        dim3 gG((ec * 128 + 255) / 256, 9);
        gate_kernel<<<gG, 256, 0, stream>>>(fijc, gp, ec);

        dim3 gO3q(1, (ec + 127) / 128, 9);
        gemm128<3, 1, false, false, true><<<gO3q, 256, 0, stream>>>(
            fijc, 128, W_post0, 128, W_post1, W_post2, nullptr, nullptr,
            out + (size_t)e0 * ND, 128, ec, 128, nullptr, nullptr, nullptr);
    }
}